// Round 7
// baseline (127.004 us; speedup 1.0000x reference)
//
#include <hip/hip_runtime.h>

#define NN 8192
#define DIN 128
#define DH 64
#define DOUT 16
#define KS 8             // K-split for gemm1

typedef _Float16 half8 __attribute__((ext_vector_type(8)));
typedef float f32x4 __attribute__((ext_vector_type(4)));

// workspace layout (bytes); ws ~1GB per harness fill evidence
#define OFF_SC    0u         // sc[4]: sx(raw max), -, -, maxH
#define OFF_PART  256u       // part[242]: per-block partial maxes; 240=Wi 241=Wo
#define OFF_YT    65536u     // Yb f16 [1024 kgrp][64 n][8]  (1 MB)  Y ints, |Y|<=384
#define OFF_RT    1114112u   // f16 [16][8192]   (256 KB) R^T, k-dim pi-permuted
#define OFF_HF    1376256u   // f32 [8192][64]   (2 MB)
#define OFF_BITS  3473408u   // u8  [8192][1024] (8 MB)   A>0 bitmask, pi-permuted cols
#define OFF_P1    11862016u  // f32 [8][8192][64] (16 MB)

// pi-permutation within each 256-element group (from float4+ballot packing):
// stored position p <-> element e = 4*(p&63) + (p>>6). Applied to bits, Yb, RT.
__device__ __forceinline__ int permk(int k) {
  int e = k & 255;
  return (k & ~255) | (((e & 3) << 6) | (e >> 2));
}

__device__ __forceinline__ float getscale(const unsigned* sc, int idx, float qmax) {
  float s = __uint_as_float(sc[idx]) / qmax;
  return (s == 0.0f) ? 1.0f : s;   // matches reference where(scale==0,1,scale)
}

__device__ __forceinline__ half8 expand8(unsigned bb) {  // 8 bits -> 8 f16 {0,1}
  uint4 w;
  w.x = ((bb & 1u)  ? 0x3C00u : 0u) | ((bb & 2u)   ? 0x3C000000u : 0u);
  w.y = ((bb & 4u)  ? 0x3C00u : 0u) | ((bb & 8u)   ? 0x3C000000u : 0u);
  w.z = ((bb & 16u) ? 0x3C00u : 0u) | ((bb & 32u)  ? 0x3C000000u : 0u);
  w.w = ((bb & 64u) ? 0x3C00u : 0u) | ((bb & 128u) ? 0x3C000000u : 0u);
  return __builtin_bit_cast(half8, w);
}

// K1: blocks [0,4096): binarize A via float4 + 4x ballot (16B/lane coalesced,
// bit order = pi permutation, free). blocks [4096,4338): abs-max partials.
__global__ __launch_bounds__(256) void k_scalesbits(const float* __restrict__ A,
                                                    const float* __restrict__ X,
                                                    const float* __restrict__ Wi,
                                                    const float* __restrict__ Wo,
                                                    unsigned char* __restrict__ bits,
                                                    unsigned* part, unsigned* sc) {
  const int t = threadIdx.x, bx = blockIdx.x;
  if (bx < 4096) {
    const int lane = t & 63, warp = t >> 6;
    const size_t wbase = ((size_t)bx * 4 + warp) * 4096;   // floats per wave
    const float4* ap = (const float4*)(A + wbase) + lane;
    unsigned char* bp = bits + (wbase >> 3);
#pragma unroll
    for (int g = 0; g < 16; ++g) {                         // 256 floats per group
      float4 v = ap[g * 64];
      unsigned long long m0 = __ballot(v.x > 0.0f);
      unsigned long long m1 = __ballot(v.y > 0.0f);
      unsigned long long m2 = __ballot(v.z > 0.0f);
      unsigned long long m3 = __ballot(v.w > 0.0f);
      unsigned long long lo = (lane & 1) ? m1 : m0;
      unsigned long long hi = (lane & 1) ? m3 : m2;
      unsigned long long word = (lane & 2) ? hi : lo;
      if (lane < 4) *(unsigned long long*)(bp + g * 32 + lane * 8) = word;
    }
    return;
  }
  __shared__ float red[256];
  const int b = bx - 4096;
  float m = 0.0f;
  if (b < 240) {
    for (int i = b * 256 + t; i < NN * DIN; i += 240 * 256) m = fmaxf(m, fabsf(X[i]));
  } else if (b == 240) {
    for (int i = t; i < DIN * DH; i += 256) m = fmaxf(m, fabsf(Wi[i]));
    if (t == 0) sc[3] = 0u;   // reset h-max for this call (ws not re-poisoned)
  } else {
    for (int i = t; i < DH * DOUT; i += 256) m = fmaxf(m, fabsf(Wo[i]));
  }
  red[t] = m; __syncthreads();
  for (int s = 128; s > 0; s >>= 1) {
    if (t < s) red[t] = fmaxf(red[t], red[t + s]);
    __syncthreads();
  }
  if (t == 0) part[b] = __float_as_uint(red[0]);
}

// K2: Yb[kp>>3][j][kp&7] = sum_n Xq_int[k][n] * Wi_int[n][j]  (exact ints)
// Wi quantized inline; sx reduced from partials in-block; block 0 publishes sc[0].
__global__ __launch_bounds__(256) void k_Y(const float* __restrict__ X,
                                           const float* __restrict__ Wi,
                                           const unsigned* __restrict__ part,
                                           unsigned* sc,
                                           _Float16* __restrict__ Yb) {
  __shared__ float red[256];
  __shared__ float Xs[8][129];
  __shared__ float Ws[DIN][DH];
  const int t = threadIdx.x;
  red[t] = (t < 240) ? __uint_as_float(part[t]) : 0.0f;
  __syncthreads();
  for (int s = 128; s > 0; s >>= 1) {
    if (t < s) red[t] = fmaxf(red[t], red[t + s]);
    __syncthreads();
  }
  float sxraw = red[0];
  float sx = sxraw / 3.0f; sx = (sx == 0.0f) ? 1.0f : sx;
  float swi = __uint_as_float(part[240]); swi = (swi == 0.0f) ? 1.0f : swi;  // qmax=1
  if (blockIdx.x == 0 && t == 0) sc[0] = __float_as_uint(sxraw);
  const int k0 = blockIdx.x * 8;
  __syncthreads();
  for (int i = t; i < 8 * DIN; i += 256) {
    int r = i >> 7, c = i & 127;
    float q = rintf(X[(size_t)(k0 + r) * DIN + c] / sx);
    Xs[r][c] = fminf(fmaxf(q, -3.0f), 3.0f);
  }
  for (int i = t; i < DIN * DH; i += 256) {
    float q = rintf(Wi[i] / swi);
    Ws[i >> 6][i & 63] = fminf(fmaxf(q, -1.0f), 1.0f);
  }
  __syncthreads();
  const int r = t & 7, jp = t >> 3, j = jp * 2;
  float a0 = 0.0f, a1 = 0.0f;
  for (int n = 0; n < DIN; ++n) {
    float xv = Xs[r][n];
    a0 = fmaf(xv, Ws[n][j], a0);
    a1 = fmaf(xv, Ws[n][j + 1], a1);
  }
  const int kp = permk(k0 + r);
  const size_t base = (size_t)(kp >> 3) * 512 + (size_t)j * 8 + (kp & 7);
  Yb[base]     = (_Float16)a0;   // exact integers in f16
  Yb[base + 8] = (_Float16)a1;
}

// K3: h_int = Aq @ Y.  BM=256 (4 waves x 64 rows), full N=64, KSPLIT=8.
// k-chunk 1024, staged as two 64KB halves into LINEAR LDS (layout matches Yb:
// [kgrp][64 n][8 f16] -> conflict-free b128 reads, no swizzle). 3 barriers total;
// waves otherwise free-running with 16 independent acc chains.
__global__ __launch_bounds__(256) void k_gemm1(const unsigned char* __restrict__ bits,
                                               const _Float16* __restrict__ Yb,
                                               float* __restrict__ P1) {
  __shared__ __align__(16) char Ls[65536];
  const int t = threadIdx.x, lane = t & 63, warp = t >> 6;
  const int row0 = blockIdx.x * 256;
  const int split = blockIdx.y;          // 0..7, k-chunk = 1024
  const int l15 = lane & 15, lq = lane >> 4;
  const int sh8 = lq * 8;

  f32x4 acc[4][4] = {};
  const char* ysrc = (const char*)Yb + (size_t)split * 131072;
  const unsigned char* bbase = bits + split * 128;

  for (int half = 0; half < 2; ++half) {
    __syncthreads();
    {  // stage 64KB (64 k-groups) from L2, fully coalesced, linear dst
      const uint4* src = (const uint4*)(ysrc + half * 65536) + t;
      uint4* dst = (uint4*)Ls + t;
#pragma unroll
      for (int p = 0; p < 16; ++p) dst[p * 256] = src[p * 256];
    }
    __syncthreads();
#pragma unroll
    for (int it = 0; it < 8; ++it) {
      uint2 w[4];
#pragma unroll
      for (int rt = 0; rt < 4; ++rt)
        w[rt] = *(const uint2*)(bbase +
                 (size_t)(row0 + warp * 64 + rt * 16 + l15) * 1024 + half * 64 + it * 8);
#pragma unroll
      for (int kk = 0; kk < 2; ++kk) {
        half8 bf[4];
#pragma unroll
        for (int nt = 0; nt < 4; ++nt)
          bf[nt] = *(const half8*)(&Ls[(it * 8 + kk * 4 + lq) * 1024 + (nt * 16 + l15) * 16]);
#pragma unroll
        for (int rt = 0; rt < 4; ++rt) {
          half8 af = expand8(((kk ? w[rt].y : w[rt].x) >> sh8) & 0xffu);
#pragma unroll
          for (int nt = 0; nt < 4; ++nt)
            acc[rt][nt] = __builtin_amdgcn_mfma_f32_16x16x32_f16(af, bf[nt], acc[rt][nt], 0, 0, 0);
        }
      }
    }
  }
  const int r4 = lq * 4;
#pragma unroll
  for (int rt = 0; rt < 4; ++rt) {
#pragma unroll
    for (int nt = 0; nt < 4; ++nt) {
#pragma unroll
      for (int i = 0; i < 4; ++i) {
        int rr = row0 + warp * 64 + rt * 16 + r4 + i;
        int cc = nt * 16 + l15;
        P1[((size_t)split * NN + rr) * DH + cc] = acc[rt][nt][i];
      }
    }
  }
}

// K4: reduce K-split partials -> h (scaled), per-block max -> atomicMax
__global__ __launch_bounds__(256) void k_h2(const float* __restrict__ P1,
                                            const unsigned* __restrict__ part,
                                            unsigned* sc, float* __restrict__ hf) {
  float sx = getscale(sc, 0, 3.0f);
  float swi = __uint_as_float(part[240]); swi = (swi == 0.0f) ? 1.0f : swi;
  float sxw = sx * swi;
  int idx = blockIdx.x * 256 + threadIdx.x;          // float4 index < 131072
  const float4* p = (const float4*)P1;
  float4 s = {0, 0, 0, 0};
#pragma unroll
  for (int sp = 0; sp < KS; ++sp) {
    float4 v = p[(size_t)sp * (NN * DH / 4) + idx];  // exact integer adds
    s.x += v.x; s.y += v.y; s.z += v.z; s.w += v.w;
  }
  s.x *= sxw; s.y *= sxw; s.z *= sxw; s.w *= sxw;
  ((float4*)hf)[idx] = s;
  float m = fmaxf(fmaxf(fabsf(s.x), fabsf(s.y)), fmaxf(fabsf(s.z), fabsf(s.w)));
  __shared__ float red[256];
  red[threadIdx.x] = m; __syncthreads();
  for (int st = 128; st > 0; st >>= 1) {
    if (threadIdx.x < st) red[threadIdx.x] = fmaxf(red[threadIdx.x], red[threadIdx.x + st]);
    __syncthreads();
  }
  if (threadIdx.x == 0) atomicMax(&sc[3], __float_as_uint(red[0]));
}

// K5: R^T[j][permk(i)] = sum_n hq_int[i][n] * Wo_int[n][j]  (|R|<=192, exact in f16)
__global__ __launch_bounds__(256) void k_R(const float* __restrict__ hf,
                                           const float* __restrict__ Wo,
                                           const unsigned* __restrict__ part,
                                           const unsigned* __restrict__ sc,
                                           _Float16* __restrict__ RT) {
  __shared__ float WoS[DH][DOUT];
  float sh = getscale(sc, 3, 3.0f);
  float swo = __uint_as_float(part[241]); swo = (swo == 0.0f) ? 1.0f : swo;
  int t = threadIdx.x;
  for (int i = t; i < DH * DOUT; i += 256) {
    float q = rintf(Wo[i] / swo);
    WoS[i >> 4][i & 15] = fminf(fmaxf(q, -1.0f), 1.0f);
  }
  __syncthreads();
  int i = blockIdx.x * 16 + (t & 15), j = t >> 4;
  const float4* hp = (const float4*)(hf + (size_t)i * DH);
  float acc = 0.0f;
#pragma unroll 4
  for (int nb = 0; nb < 16; ++nb) {
    float4 h4 = hp[nb];
    float q;
    q = fminf(fmaxf(rintf(h4.x / sh), -3.0f), 3.0f); acc = fmaf(q, WoS[nb * 4 + 0][j], acc);
    q = fminf(fmaxf(rintf(h4.y / sh), -3.0f), 3.0f); acc = fmaf(q, WoS[nb * 4 + 1][j], acc);
    q = fminf(fmaxf(rintf(h4.z / sh), -3.0f), 3.0f); acc = fmaf(q, WoS[nb * 4 + 2][j], acc);
    q = fminf(fmaxf(rintf(h4.w / sh), -3.0f), 3.0f); acc = fmaf(q, WoS[nb * 4 + 3][j], acc);
  }
  RT[(size_t)j * NN + permk(i)] = (_Float16)acc;
}

// K6: out = scale * (Aq @ R), full K in-block: BM=16, 4 warps k-split 2048 each,
// RT read direct from L2 (256 KB hot), LDS cross-warp reduce, writes out directly.
__global__ __launch_bounds__(256) void k_gemm2(const unsigned char* __restrict__ bits,
                                               const _Float16* __restrict__ RT,
                                               const unsigned* __restrict__ part,
                                               const unsigned* __restrict__ sc,
                                               float* __restrict__ out) {
  __shared__ float red2[3][16][16];
  const int t = threadIdx.x, lane = t & 63, warp = t >> 6;
  const int row0 = blockIdx.x * 16;
  const int l15 = lane & 15, lq = lane >> 4;
  const int sh8 = lq * 8;

  const unsigned char* brow = bits + (size_t)(row0 + l15) * 1024 + warp * 256;
  const _Float16* rrow = RT + (size_t)l15 * NN + warp * 2048 + lq * 8;

  f32x4 acc = {};
#pragma unroll 8
  for (int it = 0; it < 32; ++it) {
    uint2 w = *(const uint2*)(brow + it * 8);
#pragma unroll
    for (int kk = 0; kk < 2; ++kk) {
      half8 af = expand8(((kk ? w.y : w.x) >> sh8) & 0xffu);
      half8 bf = *(const half8*)(rrow + it * 64 + kk * 32);
      acc = __builtin_amdgcn_mfma_f32_16x16x32_f16(af, bf, acc, 0, 0, 0);
    }
  }
  if (warp > 0) {
#pragma unroll
    for (int i = 0; i < 4; ++i) red2[warp - 1][lq * 4 + i][l15] = acc[i];
  }
  __syncthreads();
  if (warp == 0) {
    float sh = getscale(sc, 3, 3.0f);
    float swo = __uint_as_float(part[241]); swo = (swo == 0.0f) ? 1.0f : swo;
    float s = sh * swo;
#pragma unroll
    for (int i = 0; i < 4; ++i) {
      int r = lq * 4 + i;
      float v = acc[i] + red2[0][r][l15] + red2[1][r][l15] + red2[2][r][l15];
      out[(size_t)(row0 + r) * DOUT + l15] = v * s;
    }
  }
}

extern "C" void kernel_launch(void* const* d_in, const int* in_sizes, int n_in,
                              void* d_out, int out_size, void* d_ws, size_t ws_size,
                              hipStream_t stream) {
  const float* A  = (const float*)d_in[0];
  const float* X  = (const float*)d_in[1];
  const float* Wi = (const float*)d_in[2];
  const float* Wo = (const float*)d_in[3];
  char* ws = (char*)d_ws;
  unsigned* sc        = (unsigned*)(ws + OFF_SC);
  unsigned* part      = (unsigned*)(ws + OFF_PART);
  _Float16* Yb        = (_Float16*)(ws + OFF_YT);
  _Float16* RT        = (_Float16*)(ws + OFF_RT);
  float* hf           = (float*)(ws + OFF_HF);
  unsigned char* bits = (unsigned char*)(ws + OFF_BITS);
  float* P1           = (float*)(ws + OFF_P1);
  float* out          = (float*)d_out;

  k_scalesbits<<<4338, 256, 0, stream>>>(A, X, Wi, Wo, bits, part, sc);
  k_Y<<<1024, 256, 0, stream>>>(X, Wi, part, sc, Yb);
  k_gemm1<<<dim3(NN / 256, KS), 256, 0, stream>>>(bits, Yb, P1);
  k_h2<<<NN * DH / 1024, 256, 0, stream>>>(P1, part, sc, hf);
  k_R<<<NN / 16, 256, 0, stream>>>(hf, Wo, part, sc, RT);
  k_gemm2<<<NN / 16, 256, 0, stream>>>(bits, RT, part, sc, out);
}